// Round 17
// baseline (36.864 us; speedup 1.0000x reference)
//
#include <hip/hip_runtime.h>

#define C 128
#define NPIX 16384      // 4 * 64 * 64
#define THREE_C 384

typedef unsigned short u16;
typedef unsigned int u32;
typedef short bf16x8 __attribute__((ext_vector_type(8)));
typedef float f32x4 __attribute__((ext_vector_type(4)));

__device__ __forceinline__ float bf2f(u16 h) { return __uint_as_float(((u32)h) << 16); }
__device__ __forceinline__ u16 f2bf(float f) {
    u32 b = __float_as_uint(f);
    b += 0x7FFF + ((b >> 16) & 1);          // RNE
    return (u16)(b >> 16);
}
__device__ __forceinline__ u32 pack2(float a, float b) {
    return (u32)f2bf(a) | ((u32)f2bf(b) << 16);
}

#define GST 136

// ---------------- Kernel 1: vprep ----------------
// bid < 512: v = x @ Wv (32-row tiles) + xb = bf16(x) + width.  52.2KB LDS -> 3 blocks/CU.
// bid 512/513: M^T = Wk @ Wq^T (64 d-rows each, bf16 to ws) + W_out^T conversion.
__global__ __launch_bounds__(256) void vprep_kernel(const float* __restrict__ x,
                                                    const float* __restrict__ Wqkv,
                                                    const float* __restrict__ Wwidth,
                                                    const float* __restrict__ bwidth,
                                                    const float* __restrict__ Wout,
                                                    u16* __restrict__ xbb,
                                                    u16* __restrict__ vb,
                                                    float* __restrict__ width_g,
                                                    u16* __restrict__ wot,
                                                    u16* __restrict__ mtw) {
    __shared__ u16 SL[26112];   // 52224 B
    const int bid = blockIdx.x;
    const int tid = threadIdx.x;
    const int wv = tid >> 6;
    const int l = tid & 63;
    const int l15 = l & 15;
    const int l4 = l >> 4;

    if (bid < 512) {
        u16* xs = SL;                 // [32][GST]
        u16* wt = SL + 32 * GST;      // [128][GST]
        const int task = ((bid & 7) << 6) + (bid >> 3);   // XCD-chunked
        const int p0 = task * 32;

        // stage x rows (bf16): 32 rows x 32 k-quads = 1024 tasks, 4 iters
#pragma unroll
        for (int t = 0; t < 4; ++t) {
            const int f = tid + t * 256;
            const int kq = f & 31, r = f >> 5;
            const float4 xv = *(const float4*)(x + (size_t)(p0 + r) * C + kq * 4);
            uint2 pk;
            pk.x = pack2(xv.x, xv.y);
            pk.y = pack2(xv.z, xv.w);
            *(uint2*)&xs[r * GST + kq * 4] = pk;
        }
        // stage Wv^T (bf16): 128 cols x 32 k-quads = 4096 tasks, 16 iters
#pragma unroll
        for (int t = 0; t < 16; ++t) {
            const int f = tid + t * 256;
            const int c = f & 127, kq = f >> 7;
            const float w0 = Wqkv[(size_t)(kq * 4 + 0) * THREE_C + 256 + c];
            const float w1 = Wqkv[(size_t)(kq * 4 + 1) * THREE_C + 256 + c];
            const float w2 = Wqkv[(size_t)(kq * 4 + 2) * THREE_C + 256 + c];
            const float w3 = Wqkv[(size_t)(kq * 4 + 3) * THREE_C + 256 + c];
            uint2 pk;
            pk.x = pack2(w0, w1);
            pk.y = pack2(w2, w3);
            *(uint2*)&wt[c * GST + kq * 4] = pk;
        }
        __syncthreads();

        if (tid < 32) {
            float wacc = 0.f;
#pragma unroll
            for (int kk = 0; kk < C; ++kk) wacc += bf2f(xs[tid * GST + kk]) * Wwidth[kk];
            const float z = wacc + bwidth[0];
            width_g[p0 + tid] = (1.f / (1.f + __expf(-z))) * 4.242640687f + 0.5f;
        }

        // xb dump (coalesced): 512 uint4, 2 per thread
#pragma unroll
        for (int i = 0; i < 2; ++i) {
            const int id = tid + 256 * i;
            const int r = id >> 4, c16 = id & 15;
            *(uint4*)(xbb + (size_t)(p0 + r) * C + c16 * 8) = *(const uint4*)&xs[r * GST + c16 * 8];
        }

        // v GEMM: 2 strips x 2 nf-halves over 4 waves
        const int strip = (wv & 1) * 16;
        const int nh = wv >> 1;
        bf16x8 af[4];
#pragma unroll
        for (int kf = 0; kf < 4; ++kf)
            af[kf] = *(const bf16x8*)&xs[(strip + l15) * GST + kf * 32 + l4 * 8];
        f32x4 acc[4];
#pragma unroll
        for (int i = 0; i < 4; ++i) acc[i] = (f32x4){0.f, 0.f, 0.f, 0.f};
#pragma unroll
        for (int nfi = 0; nfi < 4; ++nfi) {
            const int nf = nh * 4 + nfi;
#pragma unroll
            for (int kf = 0; kf < 4; ++kf) {
                const bf16x8 bf = *(const bf16x8*)&wt[(nf * 16 + l15) * GST + kf * 32 + l4 * 8];
                acc[nfi] = __builtin_amdgcn_mfma_f32_16x16x32_bf16(af[kf], bf, acc[nfi], 0, 0, 0);
            }
        }
#pragma unroll
        for (int nfi = 0; nfi < 4; ++nfi) {
            const int col = (nh * 4 + nfi) * 16 + l15;
#pragma unroll
            for (int r = 0; r < 4; ++r) {
                const int row = strip + l4 * 4 + r;
                vb[(size_t)(p0 + row) * C + col] = f2bf(acc[nfi][r]);
            }
        }
    } else {
        // ---- M-block: M^T[d][c] = sum_a Wk[d][a] * Wq[c][a];  Wk=Wqkv[:,128:256], Wq=Wqkv[:,0:128]
        u16* wkl = SL;                // [64][GST]  (this block's d-rows)
        u16* wql = SL + 64 * GST;     // [128][GST] (all c-rows)
        const int blk = bid - 512;    // 0 or 1
        const int d0 = blk * 64;

        // stage Wk rows d0..d0+63 (row-major bf16): 2048 f4 tasks, 8 iters
#pragma unroll
        for (int t = 0; t < 8; ++t) {
            const int f = tid + t * 256;
            const int kq = f & 31, r = f >> 5;
            const float4 wv4 = *(const float4*)(Wqkv + (size_t)(d0 + r) * THREE_C + 128 + kq * 4);
            uint2 pk;
            pk.x = pack2(wv4.x, wv4.y);
            pk.y = pack2(wv4.z, wv4.w);
            *(uint2*)&wkl[r * GST + kq * 4] = pk;
        }
        // stage Wq rows 0..127 (row-major bf16): 4096 f4 tasks, 16 iters
#pragma unroll
        for (int t = 0; t < 16; ++t) {
            const int f = tid + t * 256;
            const int kq = f & 31, r = f >> 7 == 0 ? (f >> 5) : (f >> 5);  // r = f>>5 (0..127)
            const int rr = f >> 5;
            const float4 wv4 = *(const float4*)(Wqkv + (size_t)rr * THREE_C + kq * 4);
            uint2 pk;
            pk.x = pack2(wv4.x, wv4.y);
            pk.y = pack2(wv4.z, wv4.w);
            *(uint2*)&wql[rr * GST + kq * 4] = pk;
        }
        // W_out^T conversion: 2048 uint4 over 2 blocks, 4 per thread. wot[c*128+k]=bf16(Wout[k][c])
#pragma unroll
        for (int it = 0; it < 4; ++it) {
            const int u4i = blk * 1024 + tid + 256 * it;
            const int base = u4i * 8;
            const int c = base >> 7, k0 = base & 127;
            uint4 pk;
            pk.x = pack2(Wout[(size_t)(k0 + 0) * C + c], Wout[(size_t)(k0 + 1) * C + c]);
            pk.y = pack2(Wout[(size_t)(k0 + 2) * C + c], Wout[(size_t)(k0 + 3) * C + c]);
            pk.z = pack2(Wout[(size_t)(k0 + 4) * C + c], Wout[(size_t)(k0 + 5) * C + c]);
            pk.w = pack2(Wout[(size_t)(k0 + 6) * C + c], Wout[(size_t)(k0 + 7) * C + c]);
            *(uint4*)&wot[base] = pk;
        }
        __syncthreads();

        // GEMM: wave wv -> d-strip (wv*16); nf 0..7 over c; kf 0..3 over a
        bf16x8 af[4];
#pragma unroll
        for (int kf = 0; kf < 4; ++kf)
            af[kf] = *(const bf16x8*)&wkl[(wv * 16 + l15) * GST + kf * 32 + l4 * 8];
        f32x4 acc[8];
#pragma unroll
        for (int nf = 0; nf < 8; ++nf) acc[nf] = (f32x4){0.f, 0.f, 0.f, 0.f};
#pragma unroll
        for (int nf = 0; nf < 8; ++nf) {
#pragma unroll
            for (int kf = 0; kf < 4; ++kf) {
                const bf16x8 bf = *(const bf16x8*)&wql[(nf * 16 + l15) * GST + kf * 32 + l4 * 8];
                acc[nf] = __builtin_amdgcn_mfma_f32_16x16x32_bf16(af[kf], bf, acc[nf], 0, 0, 0);
            }
        }
#pragma unroll
        for (int nf = 0; nf < 8; ++nf) {
            const int c = nf * 16 + l15;
#pragma unroll
            for (int r = 0; r < 4; ++r) {
                const int d = d0 + wv * 16 + l4 * 4 + r;
                mtw[(size_t)d * C + c] = f2bf(acc[nf][r]);
            }
        }
    }
}

// ---------------- Kernel 2: fused attention (S = x M x^T) + output projection ----------------
// One block per 8x8 tile (256 blocks, 1024 thr = 16 waves). Halo 196 -> pad 208; PV-K 224.
// LDS: Xl[208][136] | MT[128][136] | Vt[128][236] = 151.8KB.
// Reuse: TD (T bounce) = MT rows 0-63 after B2; P = Xl base, y = Xl+15104, W_out^T = MT after B4.
#define HSTRIDE 136
#define TSTRIDE 236
#define VSWZ(ch, h) ((h) ^ ((((ch) >> 3) & 3) << 3))

__global__ __launch_bounds__(1024) void attn_kernel(const u16* __restrict__ xbb,
                                                    const u16* __restrict__ vb,
                                                    const float* __restrict__ width_g,
                                                    const u16* __restrict__ wot,
                                                    const u16* __restrict__ mtw,
                                                    float* __restrict__ out) {
    __shared__ u16 SL[75904];
    __shared__ float rsum[4][64];
    __shared__ float wdl[64];
    u16* Xl = SL;                    // [208][HSTRIDE]
    u16* MT = SL + 208 * HSTRIDE;    // [128][GST]
    u16* Vt = MT + 128 * GST;        // [128][TSTRIDE]

    const int tid = threadIdx.x;
    const int wv = tid >> 6;
    const int l = tid & 63;
    const int l15 = l & 15;
    const int l4 = l >> 4;

    const int W = ((int)blockIdx.x & 7) * 32 + ((int)blockIdx.x >> 3);  // XCD-chunked
    const int b = W >> 6;
    const int t = W & 63;
    const int i0 = (t >> 3) * 8;
    const int j0 = (t & 7) * 8;
    const int pbase = b * 4096;

    if (tid < 64)
        wdl[tid] = width_g[pbase + (i0 + (tid >> 3)) * 64 + j0 + (tid & 7)];

    // ======== staging: X halo (from xb), V halo transposed, M^T copy ========
    const uint4 z4 = make_uint4(0, 0, 0, 0);
    uint4 kreg[4];
    int koff[4];
    bool kw[4];
#pragma unroll
    for (int rr = 0; rr < 4; ++rr) {
        const int f = tid + rr * 1024;
        kw[rr] = (f < 3328);
        kreg[rr] = z4;
        const int c = f & 15, h = f >> 4;
        koff[rr] = h * HSTRIDE + c * 8;
        if (kw[rr] && h < 196) {
            const int hi = (h * 2341) >> 15;          // h / 14
            const int hj = h - hi * 14;
            const int ii = i0 - 3 + hi, jj = j0 - 3 + hj;
            if (((unsigned)ii < 64u) && ((unsigned)jj < 64u))
                kreg[rr] = *(const uint4*)(xbb + (size_t)(pbase + ii * 64 + jj) * C + c * 8);
        }
    }
    uint4 va[2], vz[2];
    int vc8[2], vh[2];
    bool vw[2];
#pragma unroll
    for (int rr = 0; rr < 2; ++rr) {
        const int f = tid + rr * 1024;
        vw[rr] = (f < 1792);
        va[rr] = z4; vz[rr] = z4;
        const int c8 = f & 15, h = ((f >> 4) * 2) & 255;
        vc8[rr] = c8; vh[rr] = h;
        if (vw[rr]) {
            {
                const int hi = (h * 2341) >> 15;
                const int hj = h - hi * 14;
                const int ii = i0 - 3 + hi, jj = j0 - 3 + hj;
                if ((h < 196) && ((unsigned)ii < 64u) && ((unsigned)jj < 64u))
                    va[rr] = *(const uint4*)(vb + (size_t)(pbase + ii * 64 + jj) * C + c8 * 8);
            }
            {
                const int h1 = h + 1;
                const int hi = (h1 * 2341) >> 15;
                const int hj = h1 - hi * 14;
                const int ii = i0 - 3 + hi, jj = j0 - 3 + hj;
                if ((h1 < 196) && ((unsigned)ii < 64u) && ((unsigned)jj < 64u))
                    vz[rr] = *(const uint4*)(vb + (size_t)(pbase + ii * 64 + jj) * C + c8 * 8);
            }
        }
    }
    // M^T copy: 2048 uint4, 2 per thread (mtw row-major [d][c])
    uint4 mcp[2];
    int moff[2];
#pragma unroll
    for (int i = 0; i < 2; ++i) {
        const int id = tid + 1024 * i;
        const int d = id >> 4, c8 = id & 15;
        mcp[i] = *(const uint4*)(mtw + (size_t)d * C + c8 * 8);
        moff[i] = d * GST + c8 * 8;
    }
    // LDS writes
#pragma unroll
    for (int rr = 0; rr < 4; ++rr)
        if (kw[rr]) *(uint4*)&Xl[koff[rr]] = kreg[rr];
#pragma unroll
    for (int rr = 0; rr < 2; ++rr) {
        if (vw[rr]) {
            union { uint4 u4; u16 us[8]; } ua, uz;
            ua.u4 = va[rr]; uz.u4 = vz[rr];
            const int c8 = vc8[rr], h = vh[rr];
#pragma unroll
            for (int s = 0; s < 8; ++s) {
                const int ch = c8 * 8 + s;
                *(u32*)&Vt[ch * TSTRIDE + VSWZ(ch, h)] = (u32)ua.us[s] | ((u32)uz.us[s] << 16);
            }
        }
    }
#pragma unroll
    for (int i = 0; i < 2; ++i) *(uint4*)&MT[moff[i]] = mcp[i];
    __syncthreads();  // B1: Xl, Vt, MT staged

    // ---- T-phase: T[p][d] = sum_c x_own[p][c] * M[c][d];  B from MT rows (M^T[d][c]) ----
    const int strip = wv >> 2;                        // 0..3
    const int g = wv & 3;
    bf16x8 xf[4];
    {
        const int qr = strip * 16 + l15;
        const int hown = 45 + (qr >> 3) * 14 + (qr & 7);
#pragma unroll
        for (int kf = 0; kf < 4; ++kf)
            xf[kf] = *(const bf16x8*)&Xl[hown * HSTRIDE + kf * 32 + l4 * 8];
    }
    f32x4 tacc[2];
    tacc[0] = (f32x4){0.f, 0.f, 0.f, 0.f};
    tacc[1] = (f32x4){0.f, 0.f, 0.f, 0.f};
#pragma unroll
    for (int u = 0; u < 2; ++u) {
        const int nf = g + 4 * u;
#pragma unroll
        for (int kf = 0; kf < 4; ++kf) {
            const bf16x8 bf = *(const bf16x8*)&MT[(nf * 16 + l15) * GST + kf * 32 + l4 * 8];
            tacc[u] = __builtin_amdgcn_mfma_f32_16x16x32_bf16(xf[kf], bf, tacc[u], 0, 0, 0);
        }
    }
    __syncthreads();  // B2: all T MFMAs done (MT rows 0-63 now dead)

    // T bounce into TD = MT rows 0-63
    u16* TD = MT;
#pragma unroll
    for (int u = 0; u < 2; ++u) {
        const int col = (g + 4 * u) * 16 + l15;
#pragma unroll
        for (int r = 0; r < 4; ++r) {
            const int row = strip * 16 + l4 * 4 + r;
            TD[row * GST + col] = f2bf(tacc[u][r]);
        }
    }
    __syncthreads();  // B3: T ready

    // ---- S-phase: S = T @ x_halo^T ----
    bf16x8 tf[4];
#pragma unroll
    for (int kf = 0; kf < 4; ++kf)
        tf[kf] = *(const bf16x8*)&TD[(strip * 16 + l15) * GST + kf * 32 + l4 * 8];
    f32x4 sv[4];
#pragma unroll
    for (int tt = 0; tt < 4; ++tt) {
        const int nf = g + 4 * tt;
        f32x4 acc = {0.f, 0.f, 0.f, 0.f};
        if (nf < 13) {
            const u16* xr = Xl + (nf * 16 + l15) * HSTRIDE + l4 * 8;
#pragma unroll
            for (int kf = 0; kf < 4; ++kf)
                acc = __builtin_amdgcn_mfma_f32_16x16x32_bf16(
                    tf[kf], *(const bf16x8*)(xr + kf * 32), acc, 0, 0, 0);
        }
        sv[tt] = acc;
    }

    // W_out^T copy loads (write after B4)
    uint4 wcopy0 = *(const uint4*)(wot + tid * 8);
    uint4 wcopy1 = *(const uint4*)(wot + (tid + 1024) * 8);

    // ---- mask + penalty + direct exp + group sums (all in regs) ----
    const int qrb = strip * 16 + l4 * 4;
    float wdr[4];
#pragma unroll
    for (int r = 0; r < 4; ++r) wdr[r] = wdl[qrb + r];
    float smr[4] = {0.f, 0.f, 0.f, 0.f};
#pragma unroll
    for (int tt = 0; tt < 4; ++tt) {
        const int nf = g + 4 * tt;
        if (nf < 13) {
            const int n = nf * 16 + l15;
            const int hi = (n * 2341) >> 15;
            const int hj = n - hi * 14;
#pragma unroll
            for (int r = 0; r < 4; ++r) {
                const int qr = qrb + r;
                const int di = hi - 3 - (qr >> 3);
                const int dj = hj - 3 - (qr & 7);
                const bool valid = ((unsigned)(di + 3) <= 6u) && ((unsigned)(dj + 3) <= 6u);
                float e = 0.f;
                if (valid) {
                    const float rd = sqrtf((float)(di * di + dj * dj));
                    const float sm = 1.f / (1.f + __expf(-5.f * (wdr[r] - rd)));
                    e = __expf(sv[tt][r] * 0.08838834765f - (1.f - sm) * 10000.f);
                }
                sv[tt][r] = e;
                smr[r] += e;
            }
        }
    }
#pragma unroll
    for (int r = 0; r < 4; ++r) {
        float s = smr[r];
        s += __shfl_xor(s, 1);
        s += __shfl_xor(s, 2);
        s += __shfl_xor(s, 4);
        s += __shfl_xor(s, 8);
        smr[r] = s;
    }
    if (l15 == 0) {
#pragma unroll
        for (int r = 0; r < 4; ++r) rsum[g][qrb + r] = smr[r];
    }
    __syncthreads();  // B4: S reads of Xl/TD done; Xl + MT dead

    // ---- P (unnormalized bf16) into Xl base; y region above it; W_out^T into MT ----
    u16* Pb = Xl;                         // [64][TSTRIDE] = 15104 u16
    u16* YL = Xl + 64 * TSTRIDE;          // [64][GST]
    u16* WO = MT;                         // [128][GST]
#pragma unroll
    for (int tt = 0; tt < 4; ++tt) {
        const int nf = g + 4 * tt;
        if (nf < 13) {
            const int n = nf * 16 + l15;
#pragma unroll
            for (int r = 0; r < 4; ++r)
                Pb[(qrb + r) * TSTRIDE + n] = f2bf(sv[tt][r]);
        } else if (nf == 13) {
            const int n = 208 + l15;
#pragma unroll
            for (int r = 0; r < 4; ++r)
                Pb[(qrb + r) * TSTRIDE + n] = 0;
        }
    }
    {
        const int c0 = tid >> 4, k0 = (tid & 15) * 8;
        *(uint4*)&WO[c0 * GST + k0] = wcopy0;
        *(uint4*)&WO[(64 + c0) * GST + k0] = wcopy1;
    }
    float invr[4];
#pragma unroll
    for (int r = 0; r < 4; ++r) {
        const int qr = qrb + r;
        invr[r] = 1.f / (rsum[0][qr] + rsum[1][qr] + rsum[2][qr] + rsum[3][qr]);
    }
    __syncthreads();  // B5: P + W_out^T ready

    // ---- PV: O_u = P_u @ V (K=224) ----
    f32x4 oacc[2];
    oacc[0] = (f32x4){0.f, 0.f, 0.f, 0.f};
    oacc[1] = (f32x4){0.f, 0.f, 0.f, 0.f};
#pragma unroll
    for (int kf = 0; kf < 7; ++kf) {
        const bf16x8 pa = *(const bf16x8*)(Pb + (strip * 16 + l15) * TSTRIDE + kf * 32 + l4 * 8);
#pragma unroll
        for (int nf2 = 0; nf2 < 2; ++nf2) {
            const int ch = g * 32 + nf2 * 16 + l15;
            const bf16x8 vf = *(const bf16x8*)(Vt + ch * TSTRIDE + VSWZ(ch, kf * 32 + l4 * 8));
            oacc[nf2] = __builtin_amdgcn_mfma_f32_16x16x32_bf16(pa, vf, oacc[nf2], 0, 0, 0);
        }
    }
    // y = O_u*inv + v_own
#pragma unroll
    for (int nf2 = 0; nf2 < 2; ++nf2) {
        const int cch = g * 32 + nf2 * 16 + l15;
#pragma unroll
        for (int r = 0; r < 4; ++r) {
            const int qr = qrb + r;
            const int h = 45 + (qr >> 3) * 14 + (qr & 7);
            const float vv = bf2f(Vt[cch * TSTRIDE + VSWZ(cch, h)]);
            YL[qr * GST + cch] = f2bf(oacc[nf2][r] * invr[r] + vv);
        }
    }
    __syncthreads();  // B6: y ready

    // ---- output projection ----
    bf16x8 yf[4];
#pragma unroll
    for (int kf = 0; kf < 4; ++kf)
        yf[kf] = *(const bf16x8*)&YL[(strip * 16 + l15) * GST + kf * 32 + l4 * 8];
    f32x4 oc[2];
    oc[0] = (f32x4){0.f, 0.f, 0.f, 0.f};
    oc[1] = (f32x4){0.f, 0.f, 0.f, 0.f};
#pragma unroll
    for (int u = 0; u < 2; ++u) {
        const int nf = g + 4 * u;
#pragma unroll
        for (int kf = 0; kf < 4; ++kf) {
            const bf16x8 bf = *(const bf16x8*)&WO[(nf * 16 + l15) * GST + kf * 32 + l4 * 8];
            oc[u] = __builtin_amdgcn_mfma_f32_16x16x32_bf16(yf[kf], bf, oc[u], 0, 0, 0);
        }
    }
#pragma unroll
    for (int u = 0; u < 2; ++u) {
        const int col = (g + 4 * u) * 16 + l15;
#pragma unroll
        for (int r = 0; r < 4; ++r) {
            const int qr = qrb + r;
            const int p = pbase + (i0 + (qr >> 3)) * 64 + j0 + (qr & 7);
            out[(size_t)p * C + col] = oc[u][r];
        }
    }
}

extern "C" void kernel_launch(void* const* d_in, const int* in_sizes, int n_in,
                              void* d_out, int out_size, void* d_ws, size_t ws_size,
                              hipStream_t stream) {
    const float* x      = (const float*)d_in[0];
    const float* Wqkv   = (const float*)d_in[1];
    const float* Wwidth = (const float*)d_in[2];
    const float* bwidth = (const float*)d_in[3];
    const float* Wout   = (const float*)d_in[4];
    float* out = (float*)d_out;

    u16* xbb = (u16*)d_ws;                          // 4 MB bf16(x)
    u16* vb  = xbb + (size_t)NPIX * C;              // 4 MB bf16 v
    float* width = (float*)(vb + (size_t)NPIX * C); // 64 KB fp32
    u16* wot = (u16*)(width + NPIX);                // 32 KB bf16 W_out^T
    u16* mtw = wot + 128 * 128;                     // 32 KB bf16 M^T

    vprep_kernel<<<514, 256, 0, stream>>>(x, Wqkv, Wwidth, bwidth, Wout, xbb, vb, width, wot, mtw);
    attn_kernel<<<256, 1024, 0, stream>>>(xbb, vb, width, wot, mtw, out);
}

// Round 18
// 26.880 us; speedup vs baseline: 1.3714x; 1.3714x over previous
//
#include <hip/hip_runtime.h>

#define C 128
#define NPIX 16384      // 4 * 64 * 64
#define THREE_C 384

typedef unsigned short u16;
typedef unsigned int u32;
typedef short bf16x8 __attribute__((ext_vector_type(8)));
typedef float f32x4 __attribute__((ext_vector_type(4)));

__device__ __forceinline__ float bf2f(u16 h) { return __uint_as_float(((u32)h) << 16); }
__device__ __forceinline__ u16 f2bf(float f) {
    u32 b = __float_as_uint(f);
    b += 0x7FFF + ((b >> 16) & 1);          // RNE
    return (u16)(b >> 16);
}
__device__ __forceinline__ u32 pack2(float a, float b) {
    return (u32)f2bf(a) | ((u32)f2bf(b) << 16);
}

// ---------------- Kernel 1: qkv = x @ W_qkv via MFMA (M=16384, N=384, K=128) ----------------
// 64-row tiles. Grid 768 -> 3 blocks/CU. 256 thr = 4 waves x 16-row strips.  (R14/R16 version.)
#define GST 136

__global__ __launch_bounds__(256) void qkv_kernel(const float* __restrict__ x,
                                                  const float* __restrict__ Wqkv,
                                                  const float* __restrict__ Wwidth,
                                                  const float* __restrict__ bwidth,
                                                  const float* __restrict__ Wout,
                                                  u16* __restrict__ qb,
                                                  u16* __restrict__ kb,
                                                  u16* __restrict__ vb,
                                                  float* __restrict__ width_g,
                                                  u16* __restrict__ wot) {
    __shared__ u16 xs[64 * GST];    // 17408 B
    __shared__ u16 wt[128 * GST];   // 34816 B
    const int task = ((int)(blockIdx.x & 7)) * 96 + ((int)blockIdx.x >> 3);
    const int rb = task / 3;
    const int nb = task % 3;
    const int p0 = rb * 64;
    const int tid = threadIdx.x;
    const int wv = tid >> 6;
    const int l = tid & 63;
    const int l15 = l & 15;
    const int l4 = l >> 4;

    // stage x rows (bf16): 64 rows x 32 k-quads = 2048 tasks, 8 iters
#pragma unroll
    for (int t = 0; t < 8; ++t) {
        const int f = tid + t * 256;
        const int kq = f & 31, r = f >> 5;
        const float4 xv = *(const float4*)(x + (size_t)(p0 + r) * C + kq * 4);
        uint2 pk;
        pk.x = pack2(xv.x, xv.y);
        pk.y = pack2(xv.z, xv.w);
        *(uint2*)&xs[r * GST + kq * 4] = pk;
    }
    // stage W transposed (bf16): 128 cols x 32 k-quads = 4096 tasks, 16 iters
#pragma unroll
    for (int t = 0; t < 16; ++t) {
        const int f = tid + t * 256;
        const int c = f & 127, kq = f >> 7;
        const float w0 = Wqkv[(size_t)(kq * 4 + 0) * THREE_C + nb * 128 + c];
        const float w1 = Wqkv[(size_t)(kq * 4 + 1) * THREE_C + nb * 128 + c];
        const float w2 = Wqkv[(size_t)(kq * 4 + 2) * THREE_C + nb * 128 + c];
        const float w3 = Wqkv[(size_t)(kq * 4 + 3) * THREE_C + nb * 128 + c];
        uint2 pk;
        pk.x = pack2(w0, w1);
        pk.y = pack2(w2, w3);
        *(uint2*)&wt[c * GST + kq * 4] = pk;
    }
    // W_out^T precompute: 16384 u16 = 8 blocks x 256 thr x 8 u16 (one uint4 each).
    // Layout: wot[c*128 + k] = bf16(Wout[k][c]).
    if (task < 8) {
        const int base = (task * 256 + tid) * 8;      // u16 index
        const int c = base >> 7, k0 = base & 127;
        uint4 pk;
        pk.x = pack2(Wout[(size_t)(k0 + 0) * C + c], Wout[(size_t)(k0 + 1) * C + c]);
        pk.y = pack2(Wout[(size_t)(k0 + 2) * C + c], Wout[(size_t)(k0 + 3) * C + c]);
        pk.z = pack2(Wout[(size_t)(k0 + 4) * C + c], Wout[(size_t)(k0 + 5) * C + c]);
        pk.w = pack2(Wout[(size_t)(k0 + 6) * C + c], Wout[(size_t)(k0 + 7) * C + c]);
        *(uint4*)&wot[base] = pk;
    }
    __syncthreads();

    if (nb == 0 && tid < 64) {
        float wacc = 0.f;
#pragma unroll
        for (int kk = 0; kk < C; ++kk) wacc += bf2f(xs[tid * GST + kk]) * Wwidth[kk];
        const float z = wacc + bwidth[0];
        width_g[p0 + tid] = (1.f / (1.f + __expf(-z))) * 4.242640687f + 0.5f;
    }

    const int strip = wv * 16;
    bf16x8 af[4];
#pragma unroll
    for (int kf = 0; kf < 4; ++kf)
        af[kf] = *(const bf16x8*)&xs[(strip + l15) * GST + kf * 32 + l4 * 8];

    f32x4 acc[8];
#pragma unroll
    for (int nf = 0; nf < 8; ++nf) acc[nf] = (f32x4){0.f, 0.f, 0.f, 0.f};
#pragma unroll
    for (int nf = 0; nf < 8; ++nf) {
#pragma unroll
        for (int kf = 0; kf < 4; ++kf) {
            const bf16x8 bf = *(const bf16x8*)&wt[(nf * 16 + l15) * GST + kf * 32 + l4 * 8];
            acc[nf] = __builtin_amdgcn_mfma_f32_16x16x32_bf16(af[kf], bf, acc[nf], 0, 0, 0);
        }
    }

    u16* dst = (nb == 0) ? qb : (nb == 1) ? kb : vb;
#pragma unroll
    for (int nf = 0; nf < 8; ++nf) {
        const int col = nf * 16 + l15;
#pragma unroll
        for (int r = 0; r < 4; ++r) {
            const int row = strip + l4 * 4 + r;
            dst[(size_t)(p0 + row) * C + col] = f2bf(acc[nf][r]);
        }
    }
}

// ---------------- Kernel 2: fused MFMA tile attention + output projection ----------------
// One block per 8x8 pixel tile (256 blocks, 1024 threads = 16 waves).
// Halo 14x14 = 196, N padded 208 (13 frags), PV-K padded 224 (TSTRIDE 236).
// NO-MAX softmax (scores bounded, masked -> exp->0); P unnormalized; norm folded into PV.
// V scatter split: rr=0 pre-B1, rr=1 deferred after QK^T (overlaps matrix pipe; done pre-B2).
// Barriers: B1(stage) -> B2(P+sums+Vt complete) -> B3(y+W_out^T ready).
#define HSTRIDE 136
#define TSTRIDE 236
#define VSWZ(ch, h) ((h) ^ ((((ch) >> 3) & 3) << 3))

__global__ __launch_bounds__(1024) void attn_kernel(const u16* __restrict__ qb,
                                                    const u16* __restrict__ kb,
                                                    const u16* __restrict__ vb,
                                                    const float* __restrict__ width_g,
                                                    const u16* __restrict__ wot,
                                                    float* __restrict__ out) {
    __shared__ u16 Kl[208 * HSTRIDE];   // 56576 B (reused: W_out^T rows 0-127, y rows 128-191)
    __shared__ u16 Vt[128 * TSTRIDE];   // 60416 B
    __shared__ u16 Pl[64 * TSTRIDE];    // 30208 B
    __shared__ float rsum[4][64];
    __shared__ float wdl[64];

    const int tid = threadIdx.x;
    const int wv = tid >> 6;            // 0..15
    const int l = tid & 63;
    const int l15 = l & 15;
    const int l4 = l >> 4;

    const int W = ((int)blockIdx.x & 7) * 32 + ((int)blockIdx.x >> 3);  // XCD-chunked
    const int b = W >> 6;
    const int t = W & 63;
    const int i0 = (t >> 3) * 8;
    const int j0 = (t & 7) * 8;
    const int pbase = b * 4096;

    if (tid < 64)
        wdl[tid] = width_g[pbase + (i0 + (tid >> 3)) * 64 + j0 + (tid & 7)];

    // ======== staging: issue ALL global loads, then LDS writes ========
    const uint4 z4 = make_uint4(0, 0, 0, 0);
    // K: 3328 tasks (208h x 16oct); rows >=196 get zeros
    uint4 kreg[4];
    int koff[4];
    bool kw[4];
#pragma unroll
    for (int rr = 0; rr < 4; ++rr) {
        const int f = tid + rr * 1024;
        kw[rr] = (f < 3328);
        kreg[rr] = z4;
        const int c = f & 15, h = f >> 4;
        koff[rr] = h * HSTRIDE + c * 8;
        if (kw[rr] && h < 196) {
            const int hi = (h * 2341) >> 15;          // h / 14
            const int hj = h - hi * 14;
            const int ii = i0 - 3 + hi, jj = j0 - 3 + hj;
            if (((unsigned)ii < 64u) && ((unsigned)jj < 64u))
                kreg[rr] = *(const uint4*)(kb + (size_t)(pbase + ii * 64 + jj) * C + c * 8);
        }
    }
    // V: 1792 tasks (112 h-pairs x 16oct)
    uint4 va[2], vz[2];
    int vc8[2], vh[2];
    bool vw[2];
#pragma unroll
    for (int rr = 0; rr < 2; ++rr) {
        const int f = tid + rr * 1024;
        vw[rr] = (f < 1792);
        va[rr] = z4; vz[rr] = z4;
        const int c8 = f & 15, h = ((f >> 4) * 2) & 255;
        vc8[rr] = c8; vh[rr] = h;
        if (vw[rr]) {
            {
                const int hi = (h * 2341) >> 15;
                const int hj = h - hi * 14;
                const int ii = i0 - 3 + hi, jj = j0 - 3 + hj;
                if ((h < 196) && ((unsigned)ii < 64u) && ((unsigned)jj < 64u))
                    va[rr] = *(const uint4*)(vb + (size_t)(pbase + ii * 64 + jj) * C + c8 * 8);
            }
            {
                const int h1 = h + 1;
                const int hi = (h1 * 2341) >> 15;
                const int hj = h1 - hi * 14;
                const int ii = i0 - 3 + hi, jj = j0 - 3 + hj;
                if ((h1 < 196) && ((unsigned)ii < 64u) && ((unsigned)jj < 64u))
                    vz[rr] = *(const uint4*)(vb + (size_t)(pbase + ii * 64 + jj) * C + c8 * 8);
            }
        }
    }
    // ---- LDS writes: K (all) + V rr=0; V rr=1 deferred past QK^T ----
#pragma unroll
    for (int rr = 0; rr < 4; ++rr)
        if (kw[rr]) *(uint4*)&Kl[koff[rr]] = kreg[rr];
    {
        union { uint4 u4; u16 us[8]; } ua, uz;
        ua.u4 = va[0]; uz.u4 = vz[0];
        const int c8 = vc8[0], h = vh[0];
#pragma unroll
        for (int s = 0; s < 8; ++s) {
            const int ch = c8 * 8 + s;
            *(u32*)&Vt[ch * TSTRIDE + VSWZ(ch, h)] = (u32)ua.us[s] | ((u32)uz.us[s] << 16);
        }
    }

    // Q A-fragments direct from global
    const int strip = wv >> 2;                        // 0..3 (16 q rows each)
    const int g = wv & 3;                             // N-group / channel-quarter
    bf16x8 qf[4];
    {
        const int qr = strip * 16 + l15;
        const int p = pbase + (i0 + (qr >> 3)) * 64 + j0 + (qr & 7);
#pragma unroll
        for (int kf = 0; kf < 4; ++kf)
            qf[kf] = *(const bf16x8*)(qb + (size_t)p * C + kf * 32 + l4 * 8);
    }
    __syncthreads();  // B1: Kl + Vt(rr=0) staged

    // ---- QK^T: wave handles its strip x nf = g + 4*tt ----
    f32x4 sv[4];
#pragma unroll
    for (int tt = 0; tt < 4; ++tt) {
        const int nf = g + 4 * tt;
        f32x4 acc = {0.f, 0.f, 0.f, 0.f};
        if (nf < 13) {
            const u16* kr = Kl + (nf * 16 + l15) * HSTRIDE + l4 * 8;
#pragma unroll
            for (int kf = 0; kf < 4; ++kf)
                acc = __builtin_amdgcn_mfma_f32_16x16x32_bf16(
                    qf[kf], *(const bf16x8*)(kr + kf * 32), acc, 0, 0, 0);
        }
        sv[tt] = acc;
    }

    // deferred V rr=1 scatter (overlaps QK^T latency; PV reads only after B2)
    if (vw[1]) {
        union { uint4 u4; u16 us[8]; } ua, uz;
        ua.u4 = va[1]; uz.u4 = vz[1];
        const int c8 = vc8[1], h = vh[1];
#pragma unroll
        for (int s = 0; s < 8; ++s) {
            const int ch = c8 * 8 + s;
            *(u32*)&Vt[ch * TSTRIDE + VSWZ(ch, h)] = (u32)ua.us[s] | ((u32)uz.us[s] << 16);
        }
    }

    // issue W_out^T copy loads now (hidden under softmax); LDS writes after B2.
    uint4 wcopy0 = *(const uint4*)(wot + tid * 8);
    uint4 wcopy1 = *(const uint4*)(wot + (tid + 1024) * 8);

    // ---- mask + penalty + DIRECT exp (no max pass) + group sums + P write ----
    const int qrb = strip * 16 + l4 * 4;
    float wdr[4];
#pragma unroll
    for (int r = 0; r < 4; ++r) wdr[r] = wdl[qrb + r];
    float smr[4] = {0.f, 0.f, 0.f, 0.f};
#pragma unroll
    for (int tt = 0; tt < 4; ++tt) {
        const int nf = g + 4 * tt;
        if (nf < 13) {
            const int n = nf * 16 + l15;
            const int hi = (n * 2341) >> 15;
            const int hj = n - hi * 14;
#pragma unroll
            for (int r = 0; r < 4; ++r) {
                const int qr = qrb + r;
                const int di = hi - 3 - (qr >> 3);
                const int dj = hj - 3 - (qr & 7);
                const bool valid = ((unsigned)(di + 3) <= 6u) && ((unsigned)(dj + 3) <= 6u);
                float e = 0.f;
                if (valid) {
                    const float rd = sqrtf((float)(di * di + dj * dj));
                    const float sm = 1.f / (1.f + __expf(-5.f * (wdr[r] - rd)));
                    e = __expf(sv[tt][r] * 0.08838834765f - (1.f - sm) * 10000.f);
                }
                sv[tt][r] = e;
                smr[r] += e;
                Pl[qr * TSTRIDE + n] = f2bf(e);       // unnormalized
            }
        } else if (nf == 13) {                        // zero pad cols 208-223
            const int n = 208 + l15;
#pragma unroll
            for (int r = 0; r < 4; ++r)
                Pl[(qrb + r) * TSTRIDE + n] = 0;
        }
    }
#pragma unroll
    for (int r = 0; r < 4; ++r) {
        float s = smr[r];
        s += __shfl_xor(s, 1);
        s += __shfl_xor(s, 2);
        s += __shfl_xor(s, 4);
        s += __shfl_xor(s, 8);
        smr[r] = s;
    }
    if (l15 == 0) {
#pragma unroll
        for (int r = 0; r < 4; ++r) rsum[g][qrb + r] = smr[r];
    }
    __syncthreads();  // B2: P + sums + full Vt ready; all Kl reads done

    // ---- write W_out^T bf16 into Kl rows 0-127 (preloaded in wcopy0/1) ----
    u16* wtl = Kl;
    {
        const int c0 = tid >> 4, k0 = (tid & 15) * 8;
        *(uint4*)&wtl[c0 * GST + k0] = wcopy0;
        const int c1 = 64 + (tid >> 4);
        *(uint4*)&wtl[c1 * GST + k0] = wcopy1;
    }

    // per-row normalization factor
    float invr[4];
#pragma unroll
    for (int r = 0; r < 4; ++r) {
        const int qr = qrb + r;
        invr[r] = 1.f / (rsum[0][qr] + rsum[1][qr] + rsum[2][qr] + rsum[3][qr]);
    }

    // ---- PV: O_unnorm = P_u @ V, K = 224 (7 frags); wave: strip x channel-quarter g ----
    f32x4 oacc[2];
    oacc[0] = (f32x4){0.f, 0.f, 0.f, 0.f};
    oacc[1] = (f32x4){0.f, 0.f, 0.f, 0.f};
#pragma unroll
    for (int kf = 0; kf < 7; ++kf) {
        const bf16x8 pa = *(const bf16x8*)(Pl + (strip * 16 + l15) * TSTRIDE + kf * 32 + l4 * 8);
#pragma unroll
        for (int nf2 = 0; nf2 < 2; ++nf2) {
            const int ch = g * 32 + nf2 * 16 + l15;
            const bf16x8 vf = *(const bf16x8*)(Vt + ch * TSTRIDE + VSWZ(ch, kf * 32 + l4 * 8));
            oacc[nf2] = __builtin_amdgcn_mfma_f32_16x16x32_bf16(pa, vf, oacc[nf2], 0, 0, 0);
        }
    }

    // ---- y = O_unnorm*inv + v (bf16) into Kl rows 128-191 ----
    u16* ylds = Kl + 128 * GST;
#pragma unroll
    for (int nf2 = 0; nf2 < 2; ++nf2) {
        const int cch = g * 32 + nf2 * 16 + l15;
#pragma unroll
        for (int r = 0; r < 4; ++r) {
            const int qr = qrb + r;
            const int h = 45 + (qr >> 3) * 14 + (qr & 7);   // own pixel's halo index
            const float vv = bf2f(Vt[cch * TSTRIDE + VSWZ(cch, h)]);
            ylds[qr * GST + cch] = f2bf(oacc[nf2][r] * invr[r] + vv);
        }
    }
    __syncthreads();  // B3: y + W_out^T ready

    // ---- fused output projection: out = y @ W_out ----
    bf16x8 yf[4];
#pragma unroll
    for (int kf = 0; kf < 4; ++kf)
        yf[kf] = *(const bf16x8*)&ylds[(strip * 16 + l15) * GST + kf * 32 + l4 * 8];

    f32x4 oc[2];
    oc[0] = (f32x4){0.f, 0.f, 0.f, 0.f};
    oc[1] = (f32x4){0.f, 0.f, 0.f, 0.f};
#pragma unroll
    for (int u = 0; u < 2; ++u) {
        const int nf = g + 4 * u;
#pragma unroll
        for (int kf = 0; kf < 4; ++kf) {
            const bf16x8 bf = *(const bf16x8*)&wtl[(nf * 16 + l15) * GST + kf * 32 + l4 * 8];
            oc[u] = __builtin_amdgcn_mfma_f32_16x16x32_bf16(yf[kf], bf, oc[u], 0, 0, 0);
        }
    }
#pragma unroll
    for (int u = 0; u < 2; ++u) {
        const int col = (g + 4 * u) * 16 + l15;
#pragma unroll
        for (int r = 0; r < 4; ++r) {
            const int qr = qrb + r;
            const int p = pbase + (i0 + (qr >> 3)) * 64 + j0 + (qr & 7);
            out[(size_t)p * C + col] = oc[u][r];
        }
    }
}

extern "C" void kernel_launch(void* const* d_in, const int* in_sizes, int n_in,
                              void* d_out, int out_size, void* d_ws, size_t ws_size,
                              hipStream_t stream) {
    const float* x      = (const float*)d_in[0];
    const float* Wqkv   = (const float*)d_in[1];
    const float* Wwidth = (const float*)d_in[2];
    const float* bwidth = (const float*)d_in[3];
    const float* Wout   = (const float*)d_in[4];
    float* out = (float*)d_out;

    u16* qb = (u16*)d_ws;                           // 4 MB bf16
    u16* kb = qb + (size_t)NPIX * C;                // 4 MB bf16
    u16* vb = kb + (size_t)NPIX * C;                // 4 MB bf16
    float* width = (float*)(vb + (size_t)NPIX * C); // 64 KB fp32
    u16* wot = (u16*)(width + NPIX);                // 32 KB bf16 W_out^T

    qkv_kernel<<<768, 256, 0, stream>>>(x, Wqkv, Wwidth, bwidth, Wout, qb, kb, vb, width, wot);
    attn_kernel<<<256, 1024, 0, stream>>>(qb, kb, vb, width, wot, out);
}